// Round 10
// baseline (724.118 us; speedup 1.0000x reference)
//
#include <hip/hip_runtime.h>

#define GRID   1024
#define BLOCK  256
#define BATCH  16384
#define NJ     25
#define DEPTH  256
#define ITERS  (BATCH / GRID)   // 16

typedef short s16x8 __attribute__((ext_vector_type(8)));
typedef float f32x4 __attribute__((ext_vector_type(4)));

// fp32 -> bf16 round-to-nearest-even
__device__ __forceinline__ short f2bf(float f) {
  union { float f; unsigned u; } c; c.f = f;
  unsigned r = (c.u + 0x7FFFu + ((c.u >> 16) & 1u)) >> 16;
  return (short)r;
}
// pack two floats as bf16x2 dword (lo = first element)
__device__ __forceinline__ unsigned pk2(float lo, float hi) {
  return ((unsigned)(unsigned short)f2bf(hi) << 16) |
         (unsigned)(unsigned short)f2bf(lo);
}

#define MFMA(a, b, c) __builtin_amdgcn_mfma_f32_16x16x32_bf16((a), (b), (c), 0, 0, 0)

// async 16B global -> LDS (no dest VGPRs; lane i writes lds + 16*i)
__device__ __forceinline__ void dma16(const float* g, float* l) {
  __builtin_amdgcn_global_load_lds(
      (const __attribute__((address_space(1))) void*)g,
      (__attribute__((address_space(3))) void*)l, 16, 0, 0);
}

// Consolidation round: r4 skeleton with ONE barrier/iter and zero LDS
// round-trips besides As and S3.
//   [T] DMA elem i+1 -> Asf[buf^1]   (safe: all waves' K-reads of buf^1
//                                     finished before barrier of iter i-1)
//   [K] K-loop reads Asf[buf] (fp32, source-swizzled; f2bf at read, r9-verified)
//   [S] s3 -> S3[buf]
//   [B] __syncthreads()  -- drains own DMA (aged [K]+[S] ~4K cy) and prev
//                           stores (aged ~full iter); publishes S3 + DMA.
//   [F] in-reg per-wave softmax from S3[buf] -> pf0/pf1 directly (r5-verified)
//   [W/P/O] per td: 8-shfl web Y->B-frag (r6-verified), PV, stores.
// Eliminated vs r4: barB, Ps buffer+round-trip, Yt buffer+round-trip (main
// bank-conflict source), staging VALU + nf registers.
__global__ __launch_bounds__(BLOCK, 2)
void geo_gcn_fused(const float* __restrict__ x,
                   const float* __restrict__ w,
                   float* __restrict__ out)
{
  __shared__ float Asf[2][32][256];  // 65536 B, fp32, source-swizzled, dbuf
  __shared__ float S3[2][32][36];    //  9216 B, dbuf  -> 74752 B total

  const int tid  = threadIdx.x;
  const int wv   = tid >> 6;        // 0..3, owns cols [64*wv, 64*wv+64)
  const int lane = tid & 63;
  const int quad = lane >> 4;
  const int l16  = lane & 15;

  // ---- persistent W fragments: wf[ks][td][j] = W[ks*32+quad*8+j][wv*64+td*16+l16]
  s16x8 wf[8][4];
  {
    const int ncol = wv * 64 + l16;
#pragma unroll
    for (int ks = 0; ks < 8; ++ks)
#pragma unroll
      for (int td = 0; td < 4; ++td) {
        const float* wp = w + (size_t)(ks * 32 + quad * 8) * DEPTH + ncol + td * 16;
#pragma unroll
        for (int j = 0; j < 8; ++j)
          wf[ks][td][j] = f2bf(wp[(size_t)j * DEPTH]);
      }
  }

  const int tm_s = wv >> 1;         // s3 tile (tm_s, tn_s) per wave
  const int tn_s = wv & 1;
  const int sA   = ((quad & 1) << 5) + l16;  // shfl src lanes for the Y web
  const int sB   = sA + 16;
  const bool lo32 = (lane < 32);

  // ---- prologue: DMA element blockIdx.x into Asf[0] ----
  {
    const float* xe = x + (size_t)blockIdx.x * DEPTH;
#pragma unroll
    for (int j = 0; j < 8; ++j) {
      const int r    = wv * 8 + j;
      const int nrow = (r < NJ) ? r : (NJ - 1);   // clamped rows masked downstream
      const float* src = xe + (size_t)nrow * BATCH * DEPTH
                            + ((lane ^ (2 * (r & 7))) << 2);
      dma16(src, &Asf[0][r][0]);
    }
  }
  __syncthreads();

  for (int ib = 0; ib < ITERS; ++ib) {
    const int b   = blockIdx.x + GRID * ib;
    const int buf = ib & 1;

    // ---- [T] DMA next element into Asf[buf^1] (aged by whole K loop) ----
    if (ib + 1 < ITERS) {
      const float* xe = x + (size_t)(b + GRID) * DEPTH;
#pragma unroll
      for (int j = 0; j < 8; ++j) {
        const int r    = wv * 8 + j;
        const int nrow = (r < NJ) ? r : (NJ - 1);
        const float* src = xe + (size_t)nrow * BATCH * DEPTH
                              + ((lane ^ (2 * (r & 7))) << 2);
        dma16(src, &Asf[1 - buf][r][0]);
      }
    }

    f32x4 sacc = (f32x4){0.f, 0.f, 0.f, 0.f};
    f32x4 yacc[2][4];
#pragma unroll
    for (int i = 0; i < 2; ++i)
#pragma unroll
      for (int j = 0; j < 4; ++j) yacc[i][j] = (f32x4){0.f, 0.f, 0.f, 0.f};

    // ---- [K] 8 x K=32; fp32 swizzled reads + f2bf -> 9 MFMAs ----
#pragma unroll
    for (int ks = 0; ks < 8; ++ks) {
      const int g0 = (((4 * ks + quad) ^ (l16 & 7)) << 3);   // float offset
      f32x4 ra = *(const f32x4*)&Asf[buf][l16][g0];
      f32x4 rb = *(const f32x4*)&Asf[buf][l16][g0 + 4];
      f32x4 rc = *(const f32x4*)&Asf[buf][16 + l16][g0];
      f32x4 rd = *(const f32x4*)&Asf[buf][16 + l16][g0 + 4];
      s16x8 a0, a1;
#pragma unroll
      for (int j = 0; j < 4; ++j) {
        a0[j] = f2bf(ra[j]); a0[4 + j] = f2bf(rb[j]);
        a1[j] = f2bf(rc[j]); a1[4 + j] = f2bf(rd[j]);
      }
      sacc = MFMA(tm_s ? a1 : a0, tn_s ? a1 : a0, sacc);
#pragma unroll
      for (int td = 0; td < 4; ++td) {
        yacc[0][td] = MFMA(a0, wf[ks][td], yacc[0][td]);
        yacc[1][td] = MFMA(a1, wf[ks][td], yacc[1][td]);
      }
    }

    // ---- [S] s3 -> S3[buf] (pitch 36: 2-way max) ----
#pragma unroll
    for (int r = 0; r < 4; ++r)
      S3[buf][tm_s * 16 + quad * 4 + r][tn_s * 16 + l16] = sacc[r];

    __syncthreads();   // [B] the ONLY barrier (DMA + prev stores well aged)

    // ---- [F] in-reg softmax: lane (quad,l16) computes exactly its P-frag ----
    s16x8 pf0, pf1;
    {
      f32x4 v0a = *(const f32x4*)&S3[buf][l16][quad * 8];
      f32x4 v0b = *(const f32x4*)&S3[buf][l16][quad * 8 + 4];
      f32x4 v1a = *(const f32x4*)&S3[buf][16 + l16][quad * 8];
      f32x4 v1b = *(const f32x4*)&S3[buf][16 + l16][quad * 8 + 4];
      const float NINF = -3.0e38f;
      float mx0 = NINF, mx1 = NINF;
#pragma unroll
      for (int j = 0; j < 4; ++j) {
        const bool va = (quad * 8 + j) < NJ;
        const bool vb = (quad * 8 + 4 + j) < NJ;
        mx0 = fmaxf(mx0, va ? v0a[j] : NINF);
        mx0 = fmaxf(mx0, vb ? v0b[j] : NINF);
        mx1 = fmaxf(mx1, va ? v1a[j] : NINF);
        mx1 = fmaxf(mx1, vb ? v1b[j] : NINF);
      }
      mx0 = fmaxf(mx0, __shfl_xor(mx0, 16));
      mx0 = fmaxf(mx0, __shfl_xor(mx0, 32));
      mx1 = fmaxf(mx1, __shfl_xor(mx1, 16));
      mx1 = fmaxf(mx1, __shfl_xor(mx1, 32));
      float e0[8], e1[8], s0 = 0.f, s1 = 0.f;
#pragma unroll
      for (int j = 0; j < 4; ++j) {
        const bool va = (quad * 8 + j) < NJ;
        const bool vb = (quad * 8 + 4 + j) < NJ;
        e0[j]     = va ? __expf(v0a[j] - mx0) : 0.f;
        e0[j + 4] = vb ? __expf(v0b[j] - mx0) : 0.f;
        e1[j]     = va ? __expf(v1a[j] - mx1) : 0.f;
        e1[j + 4] = vb ? __expf(v1b[j] - mx1) : 0.f;
        s0 += e0[j] + e0[j + 4];
        s1 += e1[j] + e1[j + 4];
      }
      s0 += __shfl_xor(s0, 16);
      s0 += __shfl_xor(s0, 32);
      s1 += __shfl_xor(s1, 16);
      s1 += __shfl_xor(s1, 32);
      const float r0 = 1.0f / s0, r1 = 1.0f / s1;
#pragma unroll
      for (int j = 0; j < 8; ++j) {
        pf0[j] = f2bf(e0[j] * r0);   // P[m=l16][k=8*quad+j]
        pf1[j] = f2bf(e1[j] * r1);   // P[m=16+l16][k=8*quad+j]
      }
    }

    // ---- [W/P/O] per td: Y web -> PV -> stores (no LDS, no barrier) ----
    const f32x4 z4 = (f32x4){0.f, 0.f, 0.f, 0.f};
    float* ob = out + (size_t)b * NJ * DEPTH + wv * 64 + l16;
#pragma unroll
    for (int td = 0; td < 4; ++td) {
      // yacc C-layout -> B-frag Y[k=8*quad+j][n=wv*64+td*16+l16] via 8-shfl web
      const unsigned a0 = pk2(yacc[0][td][0], yacc[0][td][1]);
      const unsigned a1 = pk2(yacc[0][td][2], yacc[0][td][3]);
      const unsigned b0 = pk2(yacc[1][td][0], yacc[1][td][1]);
      const unsigned b1 = pk2(yacc[1][td][2], yacc[1][td][3]);
      union { unsigned u[4]; s16x8 v; } yu;
      {
        int u0, u1;
        u0 = __shfl((int)a0, sA); u1 = __shfl((int)b0, sA); yu.u[0] = lo32 ? u0 : u1;
        u0 = __shfl((int)a1, sA); u1 = __shfl((int)b1, sA); yu.u[1] = lo32 ? u0 : u1;
        u0 = __shfl((int)a0, sB); u1 = __shfl((int)b0, sB); yu.u[2] = lo32 ? u0 : u1;
        u0 = __shfl((int)a1, sB); u1 = __shfl((int)b1, sB); yu.u[3] = lo32 ? u0 : u1;
      }
      f32x4 o0 = MFMA(pf0, yu.v, z4);
      f32x4 o1 = MFMA(pf1, yu.v, z4);
#pragma unroll
      for (int r = 0; r < 4; ++r) {
        ob[(size_t)(quad * 4 + r) * DEPTH + td * 16] = o0[r];   // rows 0..15
        const int nr = 16 + quad * 4 + r;                       // rows 16..24
        if (nr < NJ) ob[(size_t)nr * DEPTH + td * 16] = o1[r];
      }
    }
    // stores + this iter's nothing-else outstanding: drained, well aged,
    // at the next iteration's single barrier.
  }
}

extern "C" void kernel_launch(void* const* d_in, const int* in_sizes, int n_in,
                              void* d_out, int out_size, void* d_ws, size_t ws_size,
                              hipStream_t stream) {
  (void)in_sizes; (void)n_in; (void)out_size; (void)d_ws; (void)ws_size;
  const float* x = (const float*)d_in[0];
  const float* w = (const float*)d_in[1];
  float* out = (float*)d_out;
  geo_gcn_fused<<<dim3(GRID), dim3(BLOCK), 0, stream>>>(x, w, out);
}

// Round 11
// 677.862 us; speedup vs baseline: 1.0682x; 1.0682x over previous
//
#include <hip/hip_runtime.h>

#define GRID   1024
#define BLOCK  256
#define BATCH  16384
#define NJ     25
#define DEPTH  256
#define ITERS  (BATCH / GRID)   // 16

typedef short s16x8 __attribute__((ext_vector_type(8)));
typedef short s16x4 __attribute__((ext_vector_type(4)));
typedef float f32x4 __attribute__((ext_vector_type(4)));

// fp32 -> bf16 round-to-nearest-even (scalar fallback, used where no pair exists)
__device__ __forceinline__ short f2bf(float f) {
  union { float f; unsigned u; } c; c.f = f;
  unsigned r = (c.u + 0x7FFFu + ((c.u >> 16) & 1u)) >> 16;
  return (short)r;
}
// HW packed conversion: dword = { bf16(hi) , bf16(lo) }, RTNE — bit-identical
// to f2bf for finite inputs, 1 instruction instead of ~6.
__device__ __forceinline__ unsigned cvtpk(float lo, float hi) {
  unsigned r;
  asm("v_cvt_pk_bf16_f32 %0, %1, %2" : "=v"(r) : "v"(lo), "v"(hi));
  return r;
}

#define MFMA(a, b, c) __builtin_amdgcn_mfma_f32_16x16x32_bf16((a), (b), (c), 0, 0, 0)

// Round-4 kernel (best measured: 712 us bench) with every paired fp32->bf16
// conversion moved to v_cvt_pk_bf16_f32. Structure untouched:
// 4 waves x 64 cols, wf[8][4] register-resident, single swizzled bf16 As,
// 2 barriers/iter, register element-prefetch, swizzled Yt, stores last.
__global__ __launch_bounds__(BLOCK, 2)
void geo_gcn_fused(const float* __restrict__ x,
                   const float* __restrict__ w,
                   float* __restrict__ out)
{
  __shared__ short As[32][256];     // 16384 B, chunk-swizzled, single buffer
  __shared__ short Ps[32][40];      //  2560 B
  __shared__ float S3[32][36];      //  4608 B
  __shared__ short Yt[4][64][32];   // 16384 B, swizzled  -> 39936 B total

  const int tid  = threadIdx.x;
  const int wv   = tid >> 6;        // 0..3, owns cols [64*wv, 64*wv+64)
  const int lane = tid & 63;
  const int quad = lane >> 4;
  const int l16  = lane & 15;

  // ---- persistent W fragments: wf[ks][td][j] = W[ks*32+quad*8+j][wv*64+td*16+l16]
  s16x8 wf[8][4];
  {
    const int ncol = wv * 64 + l16;
#pragma unroll
    for (int ks = 0; ks < 8; ++ks)
#pragma unroll
      for (int td = 0; td < 4; ++td) {
        const float* wp = w + (size_t)(ks * 32 + quad * 8) * DEPTH + ncol + td * 16;
        union { unsigned u[4]; s16x8 v; } H;
        H.u[0] = cvtpk(wp[0 * DEPTH], wp[1 * DEPTH]);
        H.u[1] = cvtpk(wp[2 * DEPTH], wp[3 * DEPTH]);
        H.u[2] = cvtpk(wp[4 * DEPTH], wp[5 * DEPTH]);
        H.u[3] = cvtpk(wp[6 * DEPTH], wp[7 * DEPTH]);
        wf[ks][td] = H.v;
      }
  }

  const int tm_s = wv >> 1;         // s3 tile (tm_s, tn_s) per wave
  const int tn_s = wv & 1;
  const int srow = tid >> 3;        // staging row 0..31 (rows >= NJ stay zero)
  const int sq   = tid & 7;         // 8 threads/row, 32 floats each
  const int ssw  = (sq ^ (srow & 7)) * 8;   // swizzled chunk offset (shorts)

  const float* xb = x + (size_t)srow * BATCH * DEPTH + sq * 8;

  // ---- prologue: stage element blockIdx.x into As ----
  {
    const float* xp = xb + (size_t)blockIdx.x * DEPTH;
#pragma unroll
    for (int c = 0; c < 4; ++c) {
      float4 c0 = make_float4(0.f, 0.f, 0.f, 0.f), c1 = c0;
      if (srow < NJ) {
        c0 = *(const float4*)(xp + c * 64);
        c1 = *(const float4*)(xp + c * 64 + 4);
      }
      union { unsigned u[4]; s16x8 v; } H;
      H.u[0] = cvtpk(c0.x, c0.y);
      H.u[1] = cvtpk(c0.z, c0.w);
      H.u[2] = cvtpk(c1.x, c1.y);
      H.u[3] = cvtpk(c1.z, c1.w);
      *(s16x8*)&As[srow][ssw + c * 64] = H.v;
    }
  }
  __syncthreads();

  for (int ib = 0; ib < ITERS; ++ib) {
    const int b = blockIdx.x + GRID * ib;

    // ---- issue NEXT element's loads; consumed after barA (aged ~0.5 iter) ----
    float4 nf[8];
#pragma unroll
    for (int i = 0; i < 8; ++i) nf[i] = make_float4(0.f, 0.f, 0.f, 0.f);
    if ((ib + 1 < ITERS) && (srow < NJ)) {
      const float* xp = xb + (size_t)(b + GRID) * DEPTH;
#pragma unroll
      for (int c = 0; c < 4; ++c) {
        nf[2 * c]     = *(const float4*)(xp + c * 64);
        nf[2 * c + 1] = *(const float4*)(xp + c * 64 + 4);
      }
    }

    f32x4 sacc = (f32x4){0.f, 0.f, 0.f, 0.f};
    f32x4 yacc[2][4];
#pragma unroll
    for (int i = 0; i < 2; ++i)
#pragma unroll
      for (int j = 0; j < 4; ++j) yacc[i][j] = (f32x4){0.f, 0.f, 0.f, 0.f};

    // ---- K loop: 8 x K=32, barrier-free, swizzled reads (2-way max, free) ----
#pragma unroll
    for (int ks = 0; ks < 8; ++ks) {
      const int co = (((ks * 4 + quad) ^ (l16 & 7)) << 3);
      s16x8 a0 = *(const s16x8*)&As[l16][co];
      s16x8 a1 = *(const s16x8*)&As[16 + l16][co];
      sacc = MFMA(tm_s ? a1 : a0, tn_s ? a1 : a0, sacc);
#pragma unroll
      for (int td = 0; td < 4; ++td) {
        yacc[0][td] = MFMA(a0, wf[ks][td], yacc[0][td]);
        yacc[1][td] = MFMA(a1, wf[ks][td], yacc[1][td]);
      }
    }

    // ---- s3 -> LDS (pitch 36: 2-way max) ----
#pragma unroll
    for (int r = 0; r < 4; ++r)
      S3[tm_s * 16 + quad * 4 + r][tn_s * 16 + l16] = sacc[r];
    __syncthreads();   // barA: all As reads done; prefetch + prev stores aged

    // ---- stage NEXT element into As (reads complete at barA) ----
    if (ib + 1 < ITERS) {
#pragma unroll
      for (int c = 0; c < 4; ++c) {
        union { unsigned u[4]; s16x8 v; } H;
        H.u[0] = cvtpk(nf[2 * c].x,     nf[2 * c].y);
        H.u[1] = cvtpk(nf[2 * c].z,     nf[2 * c].w);
        H.u[2] = cvtpk(nf[2 * c + 1].x, nf[2 * c + 1].y);
        H.u[3] = cvtpk(nf[2 * c + 1].z, nf[2 * c + 1].w);
        *(s16x8*)&As[srow][ssw + c * 64] = H.v;
      }
    }

    // ---- wave-parallel softmax: 8 lanes/row over 32 rows ----
    {
      const int row = tid >> 3, c8 = tid & 7;
      float v[4]; float mx = -3.0e38f;
#pragma unroll
      for (int i = 0; i < 4; ++i) {
        const int j = c8 + 8 * i;
        v[i] = (j < NJ) ? S3[row][j] : -3.0e38f;
        mx = fmaxf(mx, v[i]);
      }
      mx = fmaxf(mx, __shfl_xor(mx, 1));
      mx = fmaxf(mx, __shfl_xor(mx, 2));
      mx = fmaxf(mx, __shfl_xor(mx, 4));
      float e[4]; float sum = 0.f;
#pragma unroll
      for (int i = 0; i < 4; ++i) {
        const int j = c8 + 8 * i;
        e[i] = (j < NJ) ? __expf(v[i] - mx) : 0.f;
        sum += e[i];
      }
      sum += __shfl_xor(sum, 1);
      sum += __shfl_xor(sum, 2);
      sum += __shfl_xor(sum, 4);
      const float rinv = 1.0f / sum;
#pragma unroll
      for (int i = 0; i < 4; ++i)
        Ps[row][c8 + 8 * i] = f2bf(e[i] * rinv);   // scattered shorts: keep scalar
    }
    __syncthreads();   // barB: LDS-only drain (cheap)

    // ---- Y (C-layout) -> Yt, phys_chunk = logical ^ ((d>>1)&3) ----
#pragma unroll
    for (int tm = 0; tm < 2; ++tm)
#pragma unroll
      for (int td = 0; td < 4; ++td) {
        union { unsigned u[2]; s16x4 v; } HY;
        HY.u[0] = cvtpk(yacc[tm][td][0], yacc[tm][td][1]);
        HY.u[1] = cvtpk(yacc[tm][td][2], yacc[tm][td][3]);
        const int pc = (tm * 2 + (quad >> 1)) ^ ((l16 >> 1) & 3);
        *(s16x4*)&Yt[wv][td * 16 + l16][pc * 8 + (quad & 1) * 4] = HY.v;
      }
    // same-wave DS ordering: Yt writes precede this wave's Yt reads

    // ---- out_strip = P @ Y_strip; stores issued LAST, no trailing barrier ----
    s16x8 pf0 = *(const s16x8*)&Ps[l16][quad * 8];
    s16x8 pf1 = *(const s16x8*)&Ps[16 + l16][quad * 8];
    const f32x4 z4 = (f32x4){0.f, 0.f, 0.f, 0.f};
    float* ob = out + (size_t)b * NJ * DEPTH + wv * 64 + l16;
#pragma unroll
    for (int td = 0; td < 4; ++td) {
      const int pr = quad ^ ((l16 >> 1) & 3);    // conflict-free swizzled read
      s16x8 yb = *(const s16x8*)&Yt[wv][td * 16 + l16][pr * 8];
      f32x4 o0 = MFMA(pf0, yb, z4);
      f32x4 o1 = MFMA(pf1, yb, z4);
#pragma unroll
      for (int r = 0; r < 4; ++r) {
        ob[(size_t)(quad * 4 + r) * DEPTH + td * 16] = o0[r];   // rows 0..15
        const int nr = 16 + quad * 4 + r;                       // rows 16..24
        if (nr < NJ) ob[(size_t)nr * DEPTH + td * 16] = o1[r];
      }
    }
    // next iter's As reads gated by barB; stores drain at next iter's barA.
  }
}

extern "C" void kernel_launch(void* const* d_in, const int* in_sizes, int n_in,
                              void* d_out, int out_size, void* d_ws, size_t ws_size,
                              hipStream_t stream) {
  (void)in_sizes; (void)n_in; (void)out_size; (void)d_ws; (void)ws_size;
  const float* x = (const float*)d_in[0];
  const float* w = (const float*)d_in[1];
  float* out = (float*)d_out;
  geo_gcn_fused<<<dim3(GRID), dim3(BLOCK), 0, stream>>>(x, w, out);
}